// Round 7
// baseline (77.754 us; speedup 1.0000x reference)
//
#include <hip/hip_runtime.h>
#include <hip/hip_bf16.h>

#define B_ 256
#define R_ 36
#define T_ 64
#define D_ 1024

// XOR swizzles: make transposing scalar LDS stores and b128 reads <=2-way
#define SWZ64(k, c) ((c) ^ ((((k) >> 4) & 3) << 4))  // 64-wide tiles
#define SWZ32(k, b) ((b) ^ ((((k) >> 3) & 3) << 3))  // 32-wide tiles

__device__ __forceinline__ float lrelu(float x) { return x >= 0.0f ? x : 0.1f * x; }

// ---- fused input streaming: float4 loads, 1024 blocks x 256 threads ----
// blocks 0..511: cap (b = bid>>1, half = bid&1 covers 512 d's); 512..1023: img.
// rp = row parity (t>>7), dq = float4 idx within half (t&127); LDS parity combine.
__global__ __launch_bounds__(256) void input_kernel(const float* __restrict__ cap,
    const float* __restrict__ img, const int* __restrict__ lens,
    float* __restrict__ cap_mean, float* __restrict__ rowsum, float* __restrict__ rowss) {
  __shared__ float4 redA[128], redB[128];
  int bid = blockIdx.x, t = threadIdx.x;
  int rp = t >> 7, dq = t & 127;
  if (bid < 512) {
    int b = bid >> 1, half = bid & 1;
    int len = lens[b];
    const float4* src = reinterpret_cast<const float4*>(cap) +
                        (size_t)b * (T_ * D_ / 4) + half * 128 + dq;
    float4 s2 = {0, 0, 0, 0}, sm = {0, 0, 0, 0};
#pragma unroll 4
    for (int it = 0; it < 32; ++it) {
      int tt = it * 2 + rp;
      float4 v = src[(size_t)tt * 256];
      float y0 = lrelu(v.x), y1 = lrelu(v.y), y2 = lrelu(v.z), y3 = lrelu(v.w);
      s2.x += y0 * y0; s2.y += y1 * y1; s2.z += y2 * y2; s2.w += y3 * y3;
      bool in = tt < len;
      sm.x += in ? y0 : 0.0f; sm.y += in ? y1 : 0.0f;
      sm.z += in ? y2 : 0.0f; sm.w += in ? y3 : 0.0f;
    }
    if (rp) { redA[dq] = s2; redB[dq] = sm; }
    __syncthreads();
    if (!rp) {
      float4 o2 = redA[dq], om = redB[dq];
      s2.x += o2.x; s2.y += o2.y; s2.z += o2.z; s2.w += o2.w;
      sm.x += om.x; sm.y += om.y; sm.z += om.z; sm.w += om.w;
      float il = 1.0f / (float)len;
      float4 cm;
      cm.x = sm.x / (sqrtf(s2.x) + 1e-8f) * il;
      cm.y = sm.y / (sqrtf(s2.y) + 1e-8f) * il;
      cm.z = sm.z / (sqrtf(s2.z) + 1e-8f) * il;
      cm.w = sm.w / (sqrtf(s2.w) + 1e-8f) * il;
      reinterpret_cast<float4*>(cap_mean)[(size_t)b * 256 + half * 128 + dq] = cm;
    }
  } else {
    int bb = bid - 512;
    int b = bb >> 1, half = bb & 1;
    const float4* src = reinterpret_cast<const float4*>(img) +
                        (size_t)b * (R_ * D_ / 4) + half * 128 + dq;
    float4 s1 = {0, 0, 0, 0}, s2 = {0, 0, 0, 0};
#pragma unroll 4
    for (int it = 0; it < 18; ++it) {
      int r = it * 2 + rp;
      float4 v = src[(size_t)r * 256];
      float y0 = lrelu(v.x), y1 = lrelu(v.y), y2 = lrelu(v.z), y3 = lrelu(v.w);
      s1.x += y0; s1.y += y1; s1.z += y2; s1.w += y3;
      s2.x += y0 * y0; s2.y += y1 * y1; s2.z += y2 * y2; s2.w += y3 * y3;
    }
    if (rp) { redA[dq] = s1; redB[dq] = s2; }
    __syncthreads();
    if (!rp) {
      float4 o1 = redA[dq], o2 = redB[dq];
      s1.x += o1.x; s1.y += o1.y; s1.z += o1.z; s1.w += o1.w;
      s2.x += o2.x; s2.y += o2.y; s2.z += o2.z; s2.w += o2.w;
      float n0 = sqrtf(s2.x) + 1e-8f, n1 = sqrtf(s2.y) + 1e-8f;
      float n2 = sqrtf(s2.z) + 1e-8f, n3 = sqrtf(s2.w) + 1e-8f;
      float4 rs, ss;
      rs.x = s1.x / n0; rs.y = s1.y / n1; rs.z = s1.z / n2; rs.w = s1.w / n3;
      ss.x = s2.x / (n0 * n0); ss.y = s2.y / (n1 * n1);
      ss.z = s2.z / (n2 * n2); ss.w = s2.w / (n3 * n3);
      reinterpret_cast<float4*>(rowsum)[(size_t)b * 256 + half * 128 + dq] = rs;
      reinterpret_cast<float4*>(rowss)[(size_t)b * 256 + half * 128 + dq] = ss;
    }
  }
}

// ---- fused: params GEMM (blocks 0..511) + BN stats (blocks 512..527) ----
// GEMM: Ppart[kz] = cap_mean @ fc_w^T (M=256,N=2048,K=1024), split-K=4,
//   tile 64c x 64n, K-chunk 256, BK=32, k-major swizzled LDS, 4x4 acc/thread
// stats: g[d] = bn_w/sqrt(var+eps), h[d] = mu*g - bn_b
__global__ __launch_bounds__(256) void gemm_stats_kernel(
    const float* __restrict__ cap_mean, const float* __restrict__ fc_w,
    const float* __restrict__ rowsum, const float* __restrict__ rowss,
    const float* __restrict__ bn_w, const float* __restrict__ bn_b,
    float* __restrict__ Ppart, float* __restrict__ g, float* __restrict__ h) {
  __shared__ float As[32][64];  // [k][c], swizzled
  __shared__ float Bs[32][64];  // [k][n], swizzled
  __shared__ float s1[4][64], s2[4][64];
  int bid = blockIdx.x;
  int t = threadIdx.x;
  if (bid < 512) {
    int nt = bid & 31, ct = (bid >> 5) & 3, kz = bid >> 7;
    int tr = t >> 4, tc = t & 15;           // output: c-rows tr*4.., n-cols tc*4..
    int cs = t >> 2, k0 = (t & 3) << 3;     // staging: row cs, 8 k from k0
    const float* arow = cap_mean + (size_t)(ct * 64 + cs) * D_ + kz * 256;
    const float* brow = fc_w + (size_t)(nt * 64 + cs) * D_ + kz * 256;
    float acc[4][4] = {};
    int sa = SWZ64(k0, cs);
    for (int kb = 0; kb < 256; kb += 32) {
      float4 a0 = *(const float4*)&arow[kb + k0];
      float4 a1 = *(const float4*)&arow[kb + k0 + 4];
      float4 b0 = *(const float4*)&brow[kb + k0];
      float4 b1 = *(const float4*)&brow[kb + k0 + 4];
      __syncthreads();  // previous iter's readers done
      As[k0 + 0][sa] = a0.x; As[k0 + 1][sa] = a0.y; As[k0 + 2][sa] = a0.z; As[k0 + 3][sa] = a0.w;
      As[k0 + 4][sa] = a1.x; As[k0 + 5][sa] = a1.y; As[k0 + 6][sa] = a1.z; As[k0 + 7][sa] = a1.w;
      Bs[k0 + 0][sa] = b0.x; Bs[k0 + 1][sa] = b0.y; Bs[k0 + 2][sa] = b0.z; Bs[k0 + 3][sa] = b0.w;
      Bs[k0 + 4][sa] = b1.x; Bs[k0 + 5][sa] = b1.y; Bs[k0 + 6][sa] = b1.z; Bs[k0 + 7][sa] = b1.w;
      __syncthreads();
#pragma unroll
      for (int kk = 0; kk < 32; ++kk) {
        float4 av = *(const float4*)&As[kk][SWZ64(kk, tr * 4)];
        float4 bv = *(const float4*)&Bs[kk][SWZ64(kk, tc * 4)];
        acc[0][0] += av.x * bv.x; acc[0][1] += av.x * bv.y; acc[0][2] += av.x * bv.z; acc[0][3] += av.x * bv.w;
        acc[1][0] += av.y * bv.x; acc[1][1] += av.y * bv.y; acc[1][2] += av.y * bv.z; acc[1][3] += av.y * bv.w;
        acc[2][0] += av.z * bv.x; acc[2][1] += av.z * bv.y; acc[2][2] += av.z * bv.z; acc[2][3] += av.z * bv.w;
        acc[3][0] += av.w * bv.x; acc[3][1] += av.w * bv.y; acc[3][2] += av.w * bv.z; acc[3][3] += av.w * bv.w;
      }
    }
    int c = ct * 64 + tr * 4;
    int n = nt * 64 + tc * 4;
#pragma unroll
    for (int i = 0; i < 4; ++i) {
      *(float4*)&Ppart[((size_t)kz * 256 + c + i) * 2048 + n] =
          make_float4(acc[i][0], acc[i][1], acc[i][2], acc[i][3]);
    }
  } else {
    int sb = bid - 512;
    int dl = t & 63;
    int d = sb * 64 + dl;
    int bg = t >> 6;
    float cs = 0.0f, c2 = 0.0f;
    for (int b = bg * 64; b < bg * 64 + 64; ++b) {
      cs += rowsum[(size_t)b * D_ + d];
      c2 += rowss[(size_t)b * D_ + d];
    }
    s1[bg][dl] = cs;
    s2[bg][dl] = c2;
    __syncthreads();
    if (t < 64) {
      cs = s1[0][dl] + s1[1][dl] + s1[2][dl] + s1[3][dl];
      c2 = s2[0][dl] + s2[1][dl] + s2[2][dl] + s2[3][dl];
      const float inv = 1.0f / (float)(B_ * R_);
      float m = cs * inv, ex2 = c2 * inv;
      float var = ex2 - m * m;
      float gg = bn_w[d] / sqrtf(var + 1e-5f);
      g[d] = gg;
      h[d] = m * gg - bn_b[d];
    }
  }
}

// ---- fused 3-GEMM for sims numerator/denominator, split-K=16 ----
// grid (8 bt, 4 ct, 16 kz); tile 32b x 64c, K-chunk 64; base computed on the fly.
// Stages alphas/betas directly from the 4 Ppart slabs + fc_b (no params buffer).
// bt==0 blocks also emit per-(kz,c) scal partials (beta*cm, beta^2, cm^2) -> Spart.
__global__ __launch_bounds__(256) void sims_kernel(const float* __restrict__ rowsum,
    const float* __restrict__ g, const float* __restrict__ h,
    const float* __restrict__ Ppart, const float* __restrict__ fc_b,
    const float* __restrict__ cap_mean,
    float* __restrict__ Npart, float* __restrict__ Qpart, float* __restrict__ Spart) {
  __shared__ float Tb[64][32];
  __shared__ float Tacv[64][64];
  __shared__ float Ta2[64][64];
  __shared__ float Tab[64][64];
  int t = threadIdx.x;
  int bt = blockIdx.x, ct = blockIdx.y, kz = blockIdx.z;
  int k0 = kz * 64;
  int tr = t >> 4, tc = t & 15;
  int bb = t >> 3, kb = (t & 7) << 3;   // Tb staging
  int cc = t >> 2, dc = (t & 3) << 4;   // T* staging
  const float* cmrow = cap_mean + (size_t)(ct * 64 + cc) * 1024 + k0;
  const float* rsrow = rowsum + (size_t)(bt * 32 + bb) * 1024 + k0;
  size_t prowoff = (size_t)(ct * 64 + cc) * 2048 + 2 * (size_t)k0;
  const float invR = 1.0f / (float)R_;
  // stage Tb[k][b] = base (transposed, swizzled): base = rs*invR*g - h
  {
    float4 v0 = *(const float4*)&rsrow[kb];
    float4 v1 = *(const float4*)&rsrow[kb + 4];
    float4 g0 = *(const float4*)&g[k0 + kb];
    float4 g1 = *(const float4*)&g[k0 + kb + 4];
    float4 h0 = *(const float4*)&h[k0 + kb];
    float4 h1 = *(const float4*)&h[k0 + kb + 4];
    int sb = SWZ32(kb, bb);
    Tb[kb + 0][sb] = v0.x * invR * g0.x - h0.x;
    Tb[kb + 1][sb] = v0.y * invR * g0.y - h0.y;
    Tb[kb + 2][sb] = v0.z * invR * g0.z - h0.z;
    Tb[kb + 3][sb] = v0.w * invR * g0.w - h0.w;
    Tb[kb + 4][sb] = v1.x * invR * g1.x - h1.x;
    Tb[kb + 5][sb] = v1.y * invR * g1.y - h1.y;
    Tb[kb + 6][sb] = v1.z * invR * g1.z - h1.z;
    Tb[kb + 7][sb] = v1.w * invR * g1.w - h1.w;
  }
  // stage Tacv/Ta2/Tab [d][c] (swizzled), summing the 4 split-K slabs + fc_b
  int sc = SWZ64(dc, cc);
  float sBc = 0.0f, sB2 = 0.0f, scm = 0.0f;
#pragma unroll
  for (int j = 0; j < 16; j += 4) {
    int d = dc + j;
    float4 cm = *(const float4*)&cmrow[d];
    float4 p0 = *(const float4*)&fc_b[2 * (k0 + d)];
    float4 p1 = *(const float4*)&fc_b[2 * (k0 + d) + 4];
#pragma unroll
    for (int s4 = 0; s4 < 4; ++s4) {
      const float* sl = Ppart + (size_t)s4 * 524288 + prowoff + 2 * d;
      float4 q0 = *(const float4*)sl;
      float4 q1 = *(const float4*)(sl + 4);
      p0.x += q0.x; p0.y += q0.y; p0.z += q0.z; p0.w += q0.w;
      p1.x += q1.x; p1.y += q1.y; p1.z += q1.z; p1.w += q1.w;
    }
    Tacv[d + 0][sc] = p0.x * cm.x; Ta2[d + 0][sc] = p0.x * p0.x; Tab[d + 0][sc] = 2.f * p0.x * p0.y;
    Tacv[d + 1][sc] = p0.z * cm.y; Ta2[d + 1][sc] = p0.z * p0.z; Tab[d + 1][sc] = 2.f * p0.z * p0.w;
    Tacv[d + 2][sc] = p1.x * cm.z; Ta2[d + 2][sc] = p1.x * p1.x; Tab[d + 2][sc] = 2.f * p1.x * p1.y;
    Tacv[d + 3][sc] = p1.z * cm.w; Ta2[d + 3][sc] = p1.z * p1.z; Tab[d + 3][sc] = 2.f * p1.z * p1.w;
    // scal partials (betas complete here; only bt==0 stores)
    sBc += p0.y * cm.x + p0.w * cm.y + p1.y * cm.z + p1.w * cm.w;
    sB2 += p0.y * p0.y + p0.w * p0.w + p1.y * p1.y + p1.w * p1.w;
    scm += cm.x * cm.x + cm.y * cm.y + cm.z * cm.z + cm.w * cm.w;
  }
  if (bt == 0) {
    // sum across the 4 threads sharing c (consecutive lanes)
    sBc += __shfl_down(sBc, 2, 4); sBc += __shfl_down(sBc, 1, 4);
    sB2 += __shfl_down(sB2, 2, 4); sB2 += __shfl_down(sB2, 1, 4);
    scm += __shfl_down(scm, 2, 4); scm += __shfl_down(scm, 1, 4);
    if ((t & 3) == 0) {
      size_t so = ((size_t)kz * 256 + ct * 64 + cc) * 4;
      Spart[so + 0] = sBc;
      Spart[so + 1] = sB2;
      Spart[so + 2] = scm;
    }
  }
  __syncthreads();
  float accN[2][4] = {};
  float accQ[2][4] = {};
#pragma unroll 8
  for (int kk = 0; kk < 64; ++kk) {
    float2 bv = *(const float2*)&Tb[kk][SWZ32(kk, tr * 2)];
    float4 acv = *(const float4*)&Tacv[kk][SWZ64(kk, tc * 4)];
    float4 a2v = *(const float4*)&Ta2[kk][SWZ64(kk, tc * 4)];
    float4 abv = *(const float4*)&Tab[kk][SWZ64(kk, tc * 4)];
    float b0 = bv.x, b1 = bv.y;
    float q0 = b0 * b0, q1 = b1 * b1;
    accN[0][0] += b0 * acv.x; accN[0][1] += b0 * acv.y; accN[0][2] += b0 * acv.z; accN[0][3] += b0 * acv.w;
    accN[1][0] += b1 * acv.x; accN[1][1] += b1 * acv.y; accN[1][2] += b1 * acv.z; accN[1][3] += b1 * acv.w;
    accQ[0][0] += q0 * a2v.x; accQ[0][1] += q0 * a2v.y; accQ[0][2] += q0 * a2v.z; accQ[0][3] += q0 * a2v.w;
    accQ[1][0] += q1 * a2v.x; accQ[1][1] += q1 * a2v.y; accQ[1][2] += q1 * a2v.z; accQ[1][3] += q1 * a2v.w;
    accQ[0][0] += b0 * abv.x; accQ[0][1] += b0 * abv.y; accQ[0][2] += b0 * abv.z; accQ[0][3] += b0 * abv.w;
    accQ[1][0] += b1 * abv.x; accQ[1][1] += b1 * abv.y; accQ[1][2] += b1 * abv.z; accQ[1][3] += b1 * abv.w;
  }
  int br = bt * 32 + tr * 2;
  int c = ct * 64 + tc * 4;
#pragma unroll
  for (int i = 0; i < 2; ++i) {
    size_t o = ((size_t)kz * 256 + br + i) * 256 + c;
    *(float4*)&Npart[o] = make_float4(accN[i][0], accN[i][1], accN[i][2], accN[i][3]);
    *(float4*)&Qpart[o] = make_float4(accQ[i][0], accQ[i][1], accQ[i][2], accQ[i][3]);
  }
}

// ---- combine split-K partials + Spart scal partials, normalize ----
__global__ __launch_bounds__(256) void final_kernel(const float* __restrict__ Npart,
    const float* __restrict__ Qpart, const float* __restrict__ Spart,
    float* __restrict__ out) {
  int b = blockIdx.x, c = threadIdx.x;
  float sBc = 0.0f, sB2 = 0.0f, scm = 0.0f;
#pragma unroll
  for (int kz = 0; kz < 16; ++kz) {
    size_t so = ((size_t)kz * 256 + c) * 4;
    sBc += Spart[so + 0];
    sB2 += Spart[so + 1];
    scm += Spart[so + 2];
  }
  float rn = 1.0f / (sqrtf(scm) + 1e-8f);
  float N = sBc, Q = sB2;
#pragma unroll
  for (int kz = 0; kz < 16; ++kz) {
    size_t o = ((size_t)kz * 256 + b) * 256 + c;
    N += Npart[o];
    Q += Qpart[o];
  }
  out[b * 256 + c] = N * rn / (sqrtf(Q) + 1e-8f);
}

extern "C" void kernel_launch(void* const* d_in, const int* in_sizes, int n_in,
                              void* d_out, int out_size, void* d_ws, size_t ws_size,
                              hipStream_t stream) {
  const float* img = (const float*)d_in[0];
  const float* cap = (const float*)d_in[1];
  const int* lens = (const int*)d_in[2];
  const float* fc_w = (const float*)d_in[3];
  const float* fc_b = (const float*)d_in[4];
  const float* bn_w = (const float*)d_in[5];
  const float* bn_b = (const float*)d_in[6];
  float* out = (float*)d_out;
  float* ws = (float*)d_ws;

  float* cap_mean = ws;                //  262144
  float* rowsum   = ws + 262144;       //  262144
  float* rowss    = ws + 524288;       //  262144
  float* g        = ws + 786432;       //    1024
  float* h        = ws + 787456;       //    1024
  float* Spart    = ws + 788480;       //   16384 (16 kz x 256 c x 4)
  float* Ppart    = ws + 804864;       // 2097152 (4 slabs x 256 x 2048)
  float* Npart    = ws + 2902016;      // 1048576 (16 kz x 256 x 256)
  float* Qpart    = ws + 3950592;      // 1048576  -> total ~20 MB

  input_kernel<<<1024, 256, 0, stream>>>(cap, img, lens, cap_mean, rowsum, rowss);
  gemm_stats_kernel<<<528, 256, 0, stream>>>(cap_mean, fc_w, rowsum, rowss,
                                             bn_w, bn_b, Ppart, g, h);
  sims_kernel<<<dim3(8, 4, 16), 256, 0, stream>>>(rowsum, g, h, Ppart, fc_b,
                                                  cap_mean, Npart, Qpart, Spart);
  final_kernel<<<256, 256, 0, stream>>>(Npart, Qpart, Spart, out);
}

// Round 9
// 66.496 us; speedup vs baseline: 1.1693x; 1.1693x over previous
//
#include <hip/hip_runtime.h>
#include <hip/hip_bf16.h>

#define B_ 256
#define R_ 36
#define T_ 64
#define D_ 1024

// XOR swizzles
#define SWZ64(k, c) ((c) ^ ((((k) >> 4) & 3) << 4))  // 64-wide tiles (sims)
#define SWZ32(k, b) ((b) ^ ((((k) >> 3) & 3) << 3))  // 32-wide tiles (sims)
#define SWZG(k, c)  ((c) ^ ((((k) >> 3) & 3) << 2))  // gemm 128-wide tiles

__device__ __forceinline__ float lrelu(float x) { return x >= 0.0f ? x : 0.1f * x; }

// block-wide sum over 256 threads (4 waves)
__device__ __forceinline__ float block_sum(float v, float* sred) {
#pragma unroll
  for (int off = 32; off > 0; off >>= 1) v += __shfl_down(v, off, 64);
  int w = threadIdx.x >> 6;
  if ((threadIdx.x & 63) == 0) sred[w] = v;
  __syncthreads();
  float r = sred[0] + sred[1] + sred[2] + sred[3];
  __syncthreads();
  return r;
}

// ---- fused input streaming: float4 loads, 1024 blocks x 256 threads ----
__global__ __launch_bounds__(256) void input_kernel(const float* __restrict__ cap,
    const float* __restrict__ img, const int* __restrict__ lens,
    float* __restrict__ cap_mean, float* __restrict__ rowsum, float* __restrict__ rowss) {
  __shared__ float4 redA[128], redB[128];
  int bid = blockIdx.x, t = threadIdx.x;
  int rp = t >> 7, dq = t & 127;
  if (bid < 512) {
    int b = bid >> 1, half = bid & 1;
    int len = lens[b];
    const float4* src = reinterpret_cast<const float4*>(cap) +
                        (size_t)b * (T_ * D_ / 4) + half * 128 + dq;
    float4 s2 = {0, 0, 0, 0}, sm = {0, 0, 0, 0};
#pragma unroll 4
    for (int it = 0; it < 32; ++it) {
      int tt = it * 2 + rp;
      float4 v = src[(size_t)tt * 256];
      float y0 = lrelu(v.x), y1 = lrelu(v.y), y2 = lrelu(v.z), y3 = lrelu(v.w);
      s2.x += y0 * y0; s2.y += y1 * y1; s2.z += y2 * y2; s2.w += y3 * y3;
      bool in = tt < len;
      sm.x += in ? y0 : 0.0f; sm.y += in ? y1 : 0.0f;
      sm.z += in ? y2 : 0.0f; sm.w += in ? y3 : 0.0f;
    }
    if (rp) { redA[dq] = s2; redB[dq] = sm; }
    __syncthreads();
    if (!rp) {
      float4 o2 = redA[dq], om = redB[dq];
      s2.x += o2.x; s2.y += o2.y; s2.z += o2.z; s2.w += o2.w;
      sm.x += om.x; sm.y += om.y; sm.z += om.z; sm.w += om.w;
      float il = 1.0f / (float)len;
      float4 cm;
      cm.x = sm.x / (sqrtf(s2.x) + 1e-8f) * il;
      cm.y = sm.y / (sqrtf(s2.y) + 1e-8f) * il;
      cm.z = sm.z / (sqrtf(s2.z) + 1e-8f) * il;
      cm.w = sm.w / (sqrtf(s2.w) + 1e-8f) * il;
      reinterpret_cast<float4*>(cap_mean)[(size_t)b * 256 + half * 128 + dq] = cm;
    }
  } else {
    int bb = bid - 512;
    int b = bb >> 1, half = bb & 1;
    const float4* src = reinterpret_cast<const float4*>(img) +
                        (size_t)b * (R_ * D_ / 4) + half * 128 + dq;
    float4 s1 = {0, 0, 0, 0}, s2 = {0, 0, 0, 0};
#pragma unroll 4
    for (int it = 0; it < 18; ++it) {
      int r = it * 2 + rp;
      float4 v = src[(size_t)r * 256];
      float y0 = lrelu(v.x), y1 = lrelu(v.y), y2 = lrelu(v.z), y3 = lrelu(v.w);
      s1.x += y0; s1.y += y1; s1.z += y2; s1.w += y3;
      s2.x += y0 * y0; s2.y += y1 * y1; s2.z += y2 * y2; s2.w += y3 * y3;
    }
    if (rp) { redA[dq] = s1; redB[dq] = s2; }
    __syncthreads();
    if (!rp) {
      float4 o1 = redA[dq], o2 = redB[dq];
      s1.x += o1.x; s1.y += o1.y; s1.z += o1.z; s1.w += o1.w;
      s2.x += o2.x; s2.y += o2.y; s2.z += o2.z; s2.w += o2.w;
      float n0 = sqrtf(s2.x) + 1e-8f, n1 = sqrtf(s2.y) + 1e-8f;
      float n2 = sqrtf(s2.z) + 1e-8f, n3 = sqrtf(s2.w) + 1e-8f;
      float4 rs, ss;
      rs.x = s1.x / n0; rs.y = s1.y / n1; rs.z = s1.z / n2; rs.w = s1.w / n3;
      ss.x = s2.x / (n0 * n0); ss.y = s2.y / (n1 * n1);
      ss.z = s2.z / (n2 * n2); ss.w = s2.w / (n3 * n3);
      reinterpret_cast<float4*>(rowsum)[(size_t)b * 256 + half * 128 + dq] = rs;
      reinterpret_cast<float4*>(rowss)[(size_t)b * 256 + half * 128 + dq] = ss;
    }
  }
}

// ---- fused: params GEMM (blocks 0..255) + BN stats (blocks 256..271) ----
// GEMM: Ppart[kz] = cap_mean @ fc_w^T (M=256,N=2048,K=1024), split-K=8,
//   tile 128c x 128n, K-chunk 128, BK=32, 8x8 acc/thread (64 FMA : 4 b128).
//   Reads 2-way bank-free via {x, x+64} col pairs; writes via SWZG.
// stats: g[d] = bn_w/sqrt(var+eps), h[d] = mu*g - bn_b
__global__ __launch_bounds__(256) void gemm_stats_kernel(
    const float* __restrict__ cap_mean, const float* __restrict__ fc_w,
    const float* __restrict__ rowsum, const float* __restrict__ rowss,
    const float* __restrict__ bn_w, const float* __restrict__ bn_b,
    float* __restrict__ Ppart, float* __restrict__ g, float* __restrict__ h) {
  __shared__ float As[32][128];  // [k][c], SWZG
  __shared__ float Bs[32][128];  // [k][n], SWZG
  __shared__ float s1s[4][64], s2s[4][64];
  int bid = blockIdx.x;
  int t = threadIdx.x;
  if (bid < 256) {
    int nt = bid & 15, ct = (bid >> 4) & 1, kz = bid >> 5;
    int tr = t >> 4, tc = t & 15;        // out: c-rows {tr*4+i, +64}, n-cols {tc*4+j, +64}
    int ca = t >> 2, k0 = (t & 3) << 3;  // staging: rows ca & ca+64, 8 k from k0
    const float* arow0 = cap_mean + (size_t)(ct * 128 + ca) * D_ + kz * 128;
    const float* arow1 = arow0 + (size_t)64 * D_;
    const float* brow0 = fc_w + (size_t)(nt * 128 + ca) * D_ + kz * 128;
    const float* brow1 = brow0 + (size_t)64 * D_;
    float acc[8][8] = {};
    int sa0 = SWZG(k0, ca);        // k0..k0+7 share k>>3 -> constant per thread
    int sa1 = SWZG(k0, ca + 64);
    for (int kb = 0; kb < 128; kb += 32) {
      float4 a0 = *(const float4*)&arow0[kb + k0];
      float4 a1 = *(const float4*)&arow0[kb + k0 + 4];
      float4 a2 = *(const float4*)&arow1[kb + k0];
      float4 a3 = *(const float4*)&arow1[kb + k0 + 4];
      float4 b0 = *(const float4*)&brow0[kb + k0];
      float4 b1 = *(const float4*)&brow0[kb + k0 + 4];
      float4 b2 = *(const float4*)&brow1[kb + k0];
      float4 b3 = *(const float4*)&brow1[kb + k0 + 4];
      __syncthreads();  // previous iter's readers done
      As[k0 + 0][sa0] = a0.x; As[k0 + 1][sa0] = a0.y; As[k0 + 2][sa0] = a0.z; As[k0 + 3][sa0] = a0.w;
      As[k0 + 4][sa0] = a1.x; As[k0 + 5][sa0] = a1.y; As[k0 + 6][sa0] = a1.z; As[k0 + 7][sa0] = a1.w;
      As[k0 + 0][sa1] = a2.x; As[k0 + 1][sa1] = a2.y; As[k0 + 2][sa1] = a2.z; As[k0 + 3][sa1] = a2.w;
      As[k0 + 4][sa1] = a3.x; As[k0 + 5][sa1] = a3.y; As[k0 + 6][sa1] = a3.z; As[k0 + 7][sa1] = a3.w;
      Bs[k0 + 0][sa0] = b0.x; Bs[k0 + 1][sa0] = b0.y; Bs[k0 + 2][sa0] = b0.z; Bs[k0 + 3][sa0] = b0.w;
      Bs[k0 + 4][sa0] = b1.x; Bs[k0 + 5][sa0] = b1.y; Bs[k0 + 6][sa0] = b1.z; Bs[k0 + 7][sa0] = b1.w;
      Bs[k0 + 0][sa1] = b2.x; Bs[k0 + 1][sa1] = b2.y; Bs[k0 + 2][sa1] = b2.z; Bs[k0 + 3][sa1] = b2.w;
      Bs[k0 + 4][sa1] = b3.x; Bs[k0 + 5][sa1] = b3.y; Bs[k0 + 6][sa1] = b3.z; Bs[k0 + 7][sa1] = b3.w;
      __syncthreads();
#pragma unroll
      for (int kk = 0; kk < 32; ++kk) {
        int col0 = (tr * 4) ^ (((kk >> 3) & 3) << 2);
        int col1 = (tc * 4) ^ (((kk >> 3) & 3) << 2);
        float4 av0 = *(const float4*)&As[kk][col0];
        float4 av1 = *(const float4*)&As[kk][col0 + 64];
        float4 bv0 = *(const float4*)&Bs[kk][col1];
        float4 bv1 = *(const float4*)&Bs[kk][col1 + 64];
        float ar[8] = {av0.x, av0.y, av0.z, av0.w, av1.x, av1.y, av1.z, av1.w};
        float br[8] = {bv0.x, bv0.y, bv0.z, bv0.w, bv1.x, bv1.y, bv1.z, bv1.w};
#pragma unroll
        for (int i = 0; i < 8; ++i)
#pragma unroll
          for (int j = 0; j < 8; ++j) acc[i][j] += ar[i] * br[j];
      }
    }
    int cbase = ct * 128 + tr * 4;
    int nbase = nt * 128 + tc * 4;
#pragma unroll
    for (int i = 0; i < 8; ++i) {
      int c = cbase + (i & 3) + ((i >> 2) << 6);
      size_t o = ((size_t)kz * 256 + c) * 2048 + nbase;
      *(float4*)&Ppart[o] = make_float4(acc[i][0], acc[i][1], acc[i][2], acc[i][3]);
      *(float4*)&Ppart[o + 64] = make_float4(acc[i][4], acc[i][5], acc[i][6], acc[i][7]);
    }
  } else {
    int sb = bid - 256;
    int dl = t & 63;
    int d = sb * 64 + dl;
    int bg = t >> 6;
    float cs = 0.0f, c2 = 0.0f;
    for (int b = bg * 64; b < bg * 64 + 64; ++b) {
      cs += rowsum[(size_t)b * D_ + d];
      c2 += rowss[(size_t)b * D_ + d];
    }
    s1s[bg][dl] = cs;
    s2s[bg][dl] = c2;
    __syncthreads();
    if (t < 64) {
      cs = s1s[0][dl] + s1s[1][dl] + s1s[2][dl] + s1s[3][dl];
      c2 = s2s[0][dl] + s2s[1][dl] + s2s[2][dl] + s2s[3][dl];
      const float inv = 1.0f / (float)(B_ * R_);
      float m = cs * inv, ex2 = c2 * inv;
      float var = ex2 - m * m;
      float gg = bn_w[d] / sqrtf(var + 1e-5f);
      g[d] = gg;
      h[d] = m * gg - bn_b[d];
    }
  }
}

// ---- fused: reduce split-K partials + fc_b -> params; per-c scalars ----
__global__ __launch_bounds__(256) void reduce_scal_kernel(const float* __restrict__ Ppart,
    const float* __restrict__ fc_b, const float* __restrict__ cap_mean,
    float* __restrict__ params, float* __restrict__ rawC, float* __restrict__ BBc,
    float* __restrict__ rn) {
  __shared__ float sred[4], sred2[4], sred3[4];
  int c = blockIdx.x, t = threadIdx.x;
  float4 p0 = reinterpret_cast<const float4*>(fc_b)[2 * t];
  float4 p1 = reinterpret_cast<const float4*>(fc_b)[2 * t + 1];
#pragma unroll
  for (int kz = 0; kz < 8; ++kz) {
    size_t base4 = ((size_t)kz * 256 + c) * 512;
    float4 q0 = reinterpret_cast<const float4*>(Ppart)[base4 + 2 * t];
    float4 q1 = reinterpret_cast<const float4*>(Ppart)[base4 + 2 * t + 1];
    p0.x += q0.x; p0.y += q0.y; p0.z += q0.z; p0.w += q0.w;
    p1.x += q1.x; p1.y += q1.y; p1.z += q1.z; p1.w += q1.w;
  }
  reinterpret_cast<float4*>(params)[(size_t)c * 512 + 2 * t] = p0;
  reinterpret_cast<float4*>(params)[(size_t)c * 512 + 2 * t + 1] = p1;
  float4 cm = reinterpret_cast<const float4*>(cap_mean)[(size_t)c * 256 + t];
  float sBc = p0.y * cm.x + p0.w * cm.y + p1.y * cm.z + p1.w * cm.w;
  float sB2 = p0.y * p0.y + p0.w * p0.w + p1.y * p1.y + p1.w * p1.w;
  float scm = cm.x * cm.x + cm.y * cm.y + cm.z * cm.z + cm.w * cm.w;
  float a = block_sum(sBc, sred);
  float bsum = block_sum(sB2, sred2);
  float cq = block_sum(scm, sred3);
  if (t == 0) {
    rawC[c] = a;
    BBc[c] = bsum;
    rn[c] = 1.0f / (sqrtf(cq) + 1e-8f);
  }
}

// ---- fused 3-GEMM for sims numerator/denominator, split-K=16 ----
__global__ __launch_bounds__(256) void sims_kernel(const float* __restrict__ rowsum,
    const float* __restrict__ g, const float* __restrict__ h,
    const float* __restrict__ params, const float* __restrict__ cap_mean,
    float* __restrict__ Npart, float* __restrict__ Qpart) {
  __shared__ float Tb[64][32];
  __shared__ float Tacv[64][64];
  __shared__ float Ta2[64][64];
  __shared__ float Tab[64][64];
  int t = threadIdx.x;
  int bt = blockIdx.x, ct = blockIdx.y, kz = blockIdx.z;
  int k0 = kz * 64;
  int tr = t >> 4, tc = t & 15;
  int bb = t >> 3, kb = (t & 7) << 3;   // Tb staging
  int cc = t >> 2, dc = (t & 3) << 4;   // T* staging
  const float* prow = params + (size_t)(ct * 64 + cc) * 2048 + 2 * k0;
  const float* cmrow = cap_mean + (size_t)(ct * 64 + cc) * 1024 + k0;
  const float* rsrow = rowsum + (size_t)(bt * 32 + bb) * 1024 + k0;
  const float invR = 1.0f / (float)R_;
  {
    float4 v0 = *(const float4*)&rsrow[kb];
    float4 v1 = *(const float4*)&rsrow[kb + 4];
    float4 g0 = *(const float4*)&g[k0 + kb];
    float4 g1 = *(const float4*)&g[k0 + kb + 4];
    float4 h0 = *(const float4*)&h[k0 + kb];
    float4 h1 = *(const float4*)&h[k0 + kb + 4];
    int sb = SWZ32(kb, bb);
    Tb[kb + 0][sb] = v0.x * invR * g0.x - h0.x;
    Tb[kb + 1][sb] = v0.y * invR * g0.y - h0.y;
    Tb[kb + 2][sb] = v0.z * invR * g0.z - h0.z;
    Tb[kb + 3][sb] = v0.w * invR * g0.w - h0.w;
    Tb[kb + 4][sb] = v1.x * invR * g1.x - h1.x;
    Tb[kb + 5][sb] = v1.y * invR * g1.y - h1.y;
    Tb[kb + 6][sb] = v1.z * invR * g1.z - h1.z;
    Tb[kb + 7][sb] = v1.w * invR * g1.w - h1.w;
  }
  int sc = SWZ64(dc, cc);
#pragma unroll
  for (int j = 0; j < 16; j += 4) {
    int d = dc + j;
    float4 p0 = *(const float4*)&prow[2 * d];
    float4 p1 = *(const float4*)&prow[2 * d + 4];
    float4 cm = *(const float4*)&cmrow[d];
    Tacv[d + 0][sc] = p0.x * cm.x; Ta2[d + 0][sc] = p0.x * p0.x; Tab[d + 0][sc] = 2.f * p0.x * p0.y;
    Tacv[d + 1][sc] = p0.z * cm.y; Ta2[d + 1][sc] = p0.z * p0.z; Tab[d + 1][sc] = 2.f * p0.z * p0.w;
    Tacv[d + 2][sc] = p1.x * cm.z; Ta2[d + 2][sc] = p1.x * p1.x; Tab[d + 2][sc] = 2.f * p1.x * p1.y;
    Tacv[d + 3][sc] = p1.z * cm.w; Ta2[d + 3][sc] = p1.z * p1.z; Tab[d + 3][sc] = 2.f * p1.z * p1.w;
  }
  __syncthreads();
  float accN[2][4] = {};
  float accQ[2][4] = {};
#pragma unroll 8
  for (int kk = 0; kk < 64; ++kk) {
    float2 bv = *(const float2*)&Tb[kk][SWZ32(kk, tr * 2)];
    float4 acv = *(const float4*)&Tacv[kk][SWZ64(kk, tc * 4)];
    float4 a2v = *(const float4*)&Ta2[kk][SWZ64(kk, tc * 4)];
    float4 abv = *(const float4*)&Tab[kk][SWZ64(kk, tc * 4)];
    float b0 = bv.x, b1 = bv.y;
    float q0 = b0 * b0, q1 = b1 * b1;
    accN[0][0] += b0 * acv.x; accN[0][1] += b0 * acv.y; accN[0][2] += b0 * acv.z; accN[0][3] += b0 * acv.w;
    accN[1][0] += b1 * acv.x; accN[1][1] += b1 * acv.y; accN[1][2] += b1 * acv.z; accN[1][3] += b1 * acv.w;
    accQ[0][0] += q0 * a2v.x; accQ[0][1] += q0 * a2v.y; accQ[0][2] += q0 * a2v.z; accQ[0][3] += q0 * a2v.w;
    accQ[1][0] += q1 * a2v.x; accQ[1][1] += q1 * a2v.y; accQ[1][2] += q1 * a2v.z; accQ[1][3] += q1 * a2v.w;
    accQ[0][0] += b0 * abv.x; accQ[0][1] += b0 * abv.y; accQ[0][2] += b0 * abv.z; accQ[0][3] += b0 * abv.w;
    accQ[1][0] += b1 * abv.x; accQ[1][1] += b1 * abv.y; accQ[1][2] += b1 * abv.z; accQ[1][3] += b1 * abv.w;
  }
  int br = bt * 32 + tr * 2;
  int c = ct * 64 + tc * 4;
#pragma unroll
  for (int i = 0; i < 2; ++i) {
    size_t o = ((size_t)kz * 256 + br + i) * 256 + c;
    *(float4*)&Npart[o] = make_float4(accN[i][0], accN[i][1], accN[i][2], accN[i][3]);
    *(float4*)&Qpart[o] = make_float4(accQ[i][0], accQ[i][1], accQ[i][2], accQ[i][3]);
  }
}

// ---- combine split-K partials, apply per-c constants + rn, normalize ----
__global__ __launch_bounds__(256) void final_kernel(const float* __restrict__ Npart,
    const float* __restrict__ Qpart, const float* __restrict__ rawC,
    const float* __restrict__ BBc, const float* __restrict__ rn, float* __restrict__ out) {
  int b = blockIdx.x, c = threadIdx.x;
  float N = rawC[c], Q = BBc[c];
#pragma unroll
  for (int kz = 0; kz < 16; ++kz) {
    size_t o = ((size_t)kz * 256 + b) * 256 + c;
    N += Npart[o];
    Q += Qpart[o];
  }
  out[b * 256 + c] = N * rn[c] / (sqrtf(Q) + 1e-8f);
}

extern "C" void kernel_launch(void* const* d_in, const int* in_sizes, int n_in,
                              void* d_out, int out_size, void* d_ws, size_t ws_size,
                              hipStream_t stream) {
  const float* img = (const float*)d_in[0];
  const float* cap = (const float*)d_in[1];
  const int* lens = (const int*)d_in[2];
  const float* fc_w = (const float*)d_in[3];
  const float* fc_b = (const float*)d_in[4];
  const float* bn_w = (const float*)d_in[5];
  const float* bn_b = (const float*)d_in[6];
  float* out = (float*)d_out;
  float* ws = (float*)d_ws;

  float* cap_mean = ws;                //  262144
  float* rowsum   = ws + 262144;       //  262144
  float* rowss    = ws + 524288;       //  262144
  float* g        = ws + 786432;       //    1024
  float* h        = ws + 787456;       //    1024
  float* params   = ws + 788480;       //  524288
  float* rawC     = ws + 1312768;      //     256
  float* BBc      = ws + 1313024;      //     256
  float* rn       = ws + 1313280;      //     256
  float* Ppart    = ws + 1313536;      // 4194304 (8 slabs x 256 x 2048)
  float* Npart    = ws + 5507840;      // 1048576 (16 kz x 256 x 256)
  float* Qpart    = ws + 6556416;      // 1048576  -> total ~30 MB

  input_kernel<<<1024, 256, 0, stream>>>(cap, img, lens, cap_mean, rowsum, rowss);
  gemm_stats_kernel<<<272, 256, 0, stream>>>(cap_mean, fc_w, rowsum, rowss,
                                             bn_w, bn_b, Ppart, g, h);
  reduce_scal_kernel<<<256, 256, 0, stream>>>(Ppart, fc_b, cap_mean, params,
                                              rawC, BBc, rn);
  sims_kernel<<<dim3(8, 4, 16), 256, 0, stream>>>(rowsum, g, h, params, cap_mean,
                                                  Npart, Qpart);
  final_kernel<<<256, 256, 0, stream>>>(Npart, Qpart, rawC, BBc, rn, out);
}